// Round 4
// baseline (166.365 us; speedup 1.0000x reference)
//
#include <hip/hip_runtime.h>

#define NB 16   // batch
#define NN 512  // input capsules (n)
#define DI 256  // input dim (i)
#define NC 64   // output capsules (c)
#define ND 128  // capsule dim (d)
#define FO 8192 // NC*ND

// ---------------------------------------------------------------------------
// k_tr: kT[c][d][i] = kern[i][c*128 + d]   (one-time transpose, LDS-tiled)
__global__ __launch_bounds__(256) void k_tr(const float* __restrict__ kern,
                                            float* __restrict__ kT) {
  int c = blockIdx.x;        // 0..63
  int i0 = blockIdx.y * 32;  // 8 tiles of 32 i
  int tid = threadIdx.x;
  __shared__ float buf[32][129];   // [i-local][d], pad -> conflict-free reads

#pragma unroll
  for (int k = 0; k < 4; ++k) {
    int e4 = tid + k * 256;        // 0..1023
    int r = e4 >> 5, dq = e4 & 31;
    float4 v = *(const float4*)(kern + (size_t)(i0 + r) * FO + c * ND + dq * 4);
    buf[r][dq * 4 + 0] = v.x;
    buf[r][dq * 4 + 1] = v.y;
    buf[r][dq * 4 + 2] = v.z;
    buf[r][dq * 4 + 3] = v.w;
  }
  __syncthreads();
#pragma unroll
  for (int k = 0; k < 16; ++k) {
    int e = tid + k * 256;         // 0..4095
    int il = e & 31, d = e >> 5;   // d 0..127
    kT[((size_t)c * ND + d) * DI + i0 + il] = buf[il][d];
  }
}

// ---------------------------------------------------------------------------
// k_colsum: xsum_p[q][b][i] = sum over 128-n quarter of x[b][n][i]
__global__ __launch_bounds__(256) void k_colsum(const float* __restrict__ x,
                                                float* __restrict__ xsum_p) {
  int b = blockIdx.x, q = blockIdx.y;
  int tid = threadIdx.x;
  int ns = tid >> 6, i4 = tid & 63;
  float4 a = {0.f, 0.f, 0.f, 0.f};
  const float4* xp = (const float4*)(x + ((size_t)b * NN + q * 128 + ns * 32) * DI) + i4;
#pragma unroll 4
  for (int n = 0; n < 32; ++n) {
    float4 v = xp[(size_t)n * 64];
    a.x += v.x; a.y += v.y; a.z += v.z; a.w += v.w;
  }
  __shared__ float4 red[4][64];
  red[ns][i4] = a;
  __syncthreads();
  if (ns == 0) {
    float4 s0 = red[0][i4], s1 = red[1][i4], s2 = red[2][i4], s3 = red[3][i4];
    float4 s;
    s.x = s0.x + s1.x + s2.x + s3.x;
    s.y = s0.y + s1.y + s2.y + s3.y;
    s.z = s0.z + s1.z + s2.z + s3.z;
    s.w = s0.w + s1.w + s2.w + s3.w;
    ((float4*)(xsum_p + ((size_t)q * NB + b) * DI))[i4] = s;
  }
}

// ---------------------------------------------------------------------------
// k_o: per block (c, b-quad): O_raw[4,128] = Y[4,256].Kc ; O = squash -> o_ws
// y comes from y_part halves (or xsum_p/64 when FIRST). K per-lane b128.
template <bool FIRST, bool TO_OUT>
__global__ __launch_bounds__(256) void k_o(const float* __restrict__ kern,
                                           const float* __restrict__ yp,
                                           const float* __restrict__ xsum_p,
                                           float* __restrict__ o_ws,
                                           float* __restrict__ outp) {
  int c = blockIdx.x, b0 = blockIdx.y * 4;
  int tid = threadIdx.x;
  __shared__ float y_lds[4][DI];          // 4 KB
  __shared__ float4 p_lds[8][4][32];      // 16 KB partials [i-half][bb][dq]

  {
    int bb = tid >> 6, i4 = tid & 63;
    float4 v;
    if (FIRST) {
      float4 s0 = ((const float4*)(xsum_p + ((size_t)0 * NB + b0 + bb) * DI))[i4];
      float4 s1 = ((const float4*)(xsum_p + ((size_t)1 * NB + b0 + bb) * DI))[i4];
      float4 s2 = ((const float4*)(xsum_p + ((size_t)2 * NB + b0 + bb) * DI))[i4];
      float4 s3 = ((const float4*)(xsum_p + ((size_t)3 * NB + b0 + bb) * DI))[i4];
      v.x = (s0.x + s1.x + s2.x + s3.x) * (1.f / 64.f);
      v.y = (s0.y + s1.y + s2.y + s3.y) * (1.f / 64.f);
      v.z = (s0.z + s1.z + s2.z + s3.z) * (1.f / 64.f);
      v.w = (s0.w + s1.w + s2.w + s3.w) * (1.f / 64.f);
    } else {
      float4 v0 = ((const float4*)(yp + (((size_t)0 * NB + b0 + bb) * NC + c) * DI))[i4];
      float4 v1 = ((const float4*)(yp + (((size_t)1 * NB + b0 + bb) * NC + c) * DI))[i4];
      v.x = v0.x + v1.x; v.y = v0.y + v1.y; v.z = v0.z + v1.z; v.w = v0.w + v1.w;
    }
    ((float4*)&y_lds[bb][0])[i4] = v;
  }
  __syncthreads();

  // phase 1: thread = (i-half 0..7, d-quad 0..31)
  {
    int dq = tid & 31, half = tid >> 5;
    float4 acc[4];
#pragma unroll
    for (int bb = 0; bb < 4; ++bb) { acc[bb].x = acc[bb].y = acc[bb].z = acc[bb].w = 0.f; }
    const float* kp = kern + c * ND + dq * 4;
#pragma unroll 2
    for (int t = 0; t < 32; t += 4) {
      int i = half * 32 + t;
      float4 kv0 = *(const float4*)(kp + (size_t)(i + 0) * FO);
      float4 kv1 = *(const float4*)(kp + (size_t)(i + 1) * FO);
      float4 kv2 = *(const float4*)(kp + (size_t)(i + 2) * FO);
      float4 kv3 = *(const float4*)(kp + (size_t)(i + 3) * FO);
#pragma unroll
      for (int bb = 0; bb < 4; ++bb) {
        float4 yv = *(const float4*)&y_lds[bb][i];
        acc[bb].x += yv.x * kv0.x + yv.y * kv1.x + yv.z * kv2.x + yv.w * kv3.x;
        acc[bb].y += yv.x * kv0.y + yv.y * kv1.y + yv.z * kv2.y + yv.w * kv3.y;
        acc[bb].z += yv.x * kv0.z + yv.y * kv1.z + yv.z * kv2.z + yv.w * kv3.z;
        acc[bb].w += yv.x * kv0.w + yv.y * kv1.w + yv.z * kv2.w + yv.w * kv3.w;
      }
    }
#pragma unroll
    for (int bb = 0; bb < 4; ++bb) p_lds[half][bb][dq] = acc[bb];
  }
  __syncthreads();

  // combine + squash: wave per bb, lanes j<32 hold float4 of d
  {
    int bb = tid >> 6, j = tid & 63;
    if (j < 32) {
      float4 o; o.x = o.y = o.z = o.w = 0.f;
#pragma unroll
      for (int h = 0; h < 8; ++h) {
        float4 p = p_lds[h][bb][j];
        o.x += p.x; o.y += p.y; o.z += p.z; o.w += p.w;
      }
      float sq = o.x * o.x + o.y * o.y + o.z * o.z + o.w * o.w;
#pragma unroll
      for (int off = 16; off >= 1; off >>= 1) sq += __shfl_xor(sq, off, 64);
      float tot = sq + 1e-7f;
      float scale = sqrtf(tot) / (0.5f + tot);
      o.x *= scale; o.y *= scale; o.z *= scale; o.w *= scale;
      size_t base = ((size_t)(b0 + bb) * NC + c) * ND;
      ((float4*)(o_ws + base))[j] = o;
      if (TO_OUT) ((float4*)(outp + base))[j] = o;
    }
  }
}

// ---------------------------------------------------------------------------
// k_w: wT[b][i][c] = sum_d o[b,c,d] * kT[c][d][i].  lane = i (coalesced kT),
// o via wave-uniform loads (SGPR broadcasts). Block (c, b-quad).
__global__ __launch_bounds__(256) void k_w(const float* __restrict__ kT,
                                           const float* __restrict__ o_ws,
                                           float* __restrict__ wT) {
  int c = blockIdx.x, b0 = blockIdx.y * 4;
  int i = threadIdx.x;
  float acc[4] = {0.f, 0.f, 0.f, 0.f};
  const float* kTc = kT + (size_t)c * ND * DI;
#pragma unroll 1
  for (int d0 = 0; d0 < ND; d0 += 4) {
    float kv0 = kTc[(size_t)(d0 + 0) * DI + i];
    float kv1 = kTc[(size_t)(d0 + 1) * DI + i];
    float kv2 = kTc[(size_t)(d0 + 2) * DI + i];
    float kv3 = kTc[(size_t)(d0 + 3) * DI + i];
#pragma unroll
    for (int bb = 0; bb < 4; ++bb) {
      float4 ov = *(const float4*)(o_ws + ((size_t)(b0 + bb) * NC + c) * ND + d0);
      acc[bb] += kv0 * ov.x + kv1 * ov.y + kv2 * ov.z + kv3 * ov.w;
    }
  }
#pragma unroll
  for (int bb = 0; bb < 4; ++bb)
    wT[((size_t)(b0 + bb) * DI + i) * NC + c] = acc[bb];
}

// ---------------------------------------------------------------------------
// k_route: b_new[b,c,n] = (ADD_B ? b_old : 0) + sum_i x[b,n,i]*wT[b,i,c]
// lane = c; wT coalesced b32; x rows via wave-uniform float4 loads (SGPR).
// softmax over c (= lanes). No LDS, no barriers. Block (b, 32-n tile).
template <bool ADD_B>
__global__ __launch_bounds__(256) void k_route(const float* __restrict__ x,
                                               const float* __restrict__ wT,
                                               float* __restrict__ blog,
                                               float* __restrict__ coef) {
  int b = blockIdx.x, n0 = blockIdx.y * 32;
  int tid = threadIdx.x;
  int lane = tid & 63;
  int w4 = __builtin_amdgcn_readfirstlane(tid >> 6);  // wave id, provably uniform
  const float* xn0 = x + ((size_t)b * NN + n0 + w4 * 8) * DI;
  const float* wTb = wT + (size_t)b * DI * NC;
  float acc[8];
#pragma unroll
  for (int k = 0; k < 8; ++k) acc[k] = 0.f;

#pragma unroll 1
  for (int ic = 0; ic < 32; ++ic) {
    int i0 = ic * 8;
    float wv[8];
#pragma unroll
    for (int j = 0; j < 8; ++j) wv[j] = wTb[(size_t)(i0 + j) * NC + lane];
#pragma unroll
    for (int nn = 0; nn < 8; ++nn) {
      const float* xn = xn0 + (size_t)nn * DI + i0;
      float4 xa = *(const float4*)(xn);       // uniform -> s_load
      float4 xb = *(const float4*)(xn + 4);
      acc[nn] += xa.x * wv[0] + xa.y * wv[1] + xa.z * wv[2] + xa.w * wv[3] +
                 xb.x * wv[4] + xb.y * wv[5] + xb.z * wv[6] + xb.w * wv[7];
    }
  }

#pragma unroll
  for (int nn = 0; nn < 8; ++nn) {
    int n = n0 + w4 * 8 + nn;
    size_t idx = ((size_t)b * NN + n) * NC + lane;
    float v = acc[nn];
    if (ADD_B) v += blog[idx];
    blog[idx] = v;
    float m = v;
#pragma unroll
    for (int off = 32; off >= 1; off >>= 1) m = fmaxf(m, __shfl_xor(m, off, 64));
    float e = __expf(v - m);
    float s = e;
#pragma unroll
    for (int off = 32; off >= 1; off >>= 1) s += __shfl_xor(s, off, 64);
    coef[idx] = e / s;
  }
}

// ---------------------------------------------------------------------------
// k_y: y_part[half][b][c0..c0+7][i] = sum over 256-n half of coef*x.
// lane = i (coalesced x); coef via wave-uniform loads. Block (b, c-oct, half).
__global__ __launch_bounds__(256) void k_y(const float* __restrict__ x,
                                           const float* __restrict__ coef,
                                           float* __restrict__ yp) {
  int b = blockIdx.x;
  int c0 = (blockIdx.y & 7) * 8;
  int half = blockIdx.y >> 3;
  int i = threadIdx.x;
  const float* xb = x + ((size_t)b * NN + half * 256) * DI;
  const float* cb = coef + ((size_t)b * NN + half * 256) * NC + c0;
  float a[8];
#pragma unroll
  for (int k = 0; k < 8; ++k) a[k] = 0.f;
#pragma unroll 2
  for (int n = 0; n < 256; ++n) {
    float xv = xb[(size_t)n * DI + i];
    float4 ca = *(const float4*)(cb + (size_t)n * NC);      // uniform -> s_load
    float4 cd = *(const float4*)(cb + (size_t)n * NC + 4);
    a[0] += xv * ca.x; a[1] += xv * ca.y; a[2] += xv * ca.z; a[3] += xv * ca.w;
    a[4] += xv * cd.x; a[5] += xv * cd.y; a[6] += xv * cd.z; a[7] += xv * cd.w;
  }
#pragma unroll
  for (int cc = 0; cc < 8; ++cc)
    yp[(((size_t)half * NB + b) * NC + c0 + cc) * DI + i] = a[cc];
}

// ---------------------------------------------------------------------------
extern "C" void kernel_launch(void* const* d_in, const int* in_sizes, int n_in,
                              void* d_out, int out_size, void* d_ws, size_t ws_size,
                              hipStream_t stream) {
  (void)in_sizes; (void)n_in; (void)out_size; (void)ws_size;
  const float* x    = (const float*)d_in[0];   // [16,512,256]
  const float* kern = (const float*)d_in[1];   // [256,8192]
  float* out = (float*)d_out;                  // [16,64,128]

  float* xsum_p = (float*)d_ws;                // 4*16*256    = 16384
  float* o_ws   = xsum_p + 4 * NB * DI;        // 16*64*128   = 131072
  float* wT     = o_ws + NB * NC * ND;         // 16*256*64   = 262144
  float* blog   = wT + NB * DI * NC;           // 16*512*64   = 524288
  float* coef   = blog + NB * NN * NC;         // 16*512*64   = 524288
  float* y_part = coef + NB * NN * NC;         // 2*16*64*256 = 524288
  float* kT     = y_part + 2 * NB * NC * DI;   // 64*128*256  = 2097152

  k_tr<<<dim3(NC, 8), 256, 0, stream>>>(kern, kT);
  k_colsum<<<dim3(NB, 4), 256, 0, stream>>>(x, xsum_p);

  // iteration 0: uniform coefficients -> o0 -> wT0
  k_o<true, false><<<dim3(NC, 4), 256, 0, stream>>>(kern, y_part, xsum_p, o_ws, out);
  k_w<<<dim3(NC, 4), 256, 0, stream>>>(kT, o_ws, wT);
  k_route<false><<<dim3(NB, 16), 256, 0, stream>>>(x, wT, blog, coef);

  // iteration 1
  k_y<<<dim3(NB, 16), 256, 0, stream>>>(x, coef, y_part);
  k_o<false, false><<<dim3(NC, 4), 256, 0, stream>>>(kern, y_part, xsum_p, o_ws, out);
  k_w<<<dim3(NC, 4), 256, 0, stream>>>(kT, o_ws, wT);
  k_route<true><<<dim3(NB, 16), 256, 0, stream>>>(x, wT, blog, coef);

  // iteration 2 (final)
  k_y<<<dim3(NB, 16), 256, 0, stream>>>(x, coef, y_part);
  k_o<false, true><<<dim3(NC, 4), 256, 0, stream>>>(kern, y_part, xsum_p, o_ws, out);
}